// Round 7
// baseline (114.278 us; speedup 1.0000x reference)
//
#include <hip/hip_runtime.h>

#define WPB 2                // waves (rays) per block (R5: finer block granularity)
#define BLOCK (64 * WPB)
#define SC 256               // coarse samples per ray
#define SF 128               // fine (importance) samples per ray

typedef float v2f __attribute__((ext_vector_type(2)));
typedef float v4f __attribute__((ext_vector_type(4)));

__device__ __forceinline__ float fexp2(float x) {
#if __has_builtin(__builtin_amdgcn_exp2f)
    return __builtin_amdgcn_exp2f(x);
#else
    return exp2f(x);
#endif
}
__device__ __forceinline__ float frcp(float x) {
#if __has_builtin(__builtin_amdgcn_rcpf)
    return __builtin_amdgcn_rcpf(x);
#else
    return 1.0f / x;
#endif
}
__device__ __forceinline__ float frsq(float x) {
#if __has_builtin(__builtin_amdgcn_rsqf)
    return __builtin_amdgcn_rsqf(x);
#else
    return rsqrtf(x);
#endif
}

// DPP move. bc=false: invalid/masked lanes read `oldv`.
// bc=true: invalid source lanes read 0 (masked rows still return oldv).
#define DPPF(oldv, x, ctrl, rmask, bc)                                          \
    __int_as_float(__builtin_amdgcn_update_dpp(                                 \
        __float_as_int(oldv), __float_as_int(x), (ctrl), (rmask), 0xf, (bc)))

// gfx9 DPP ctrl codes
#define ROW_SHR1   0x111
#define ROW_SHR2   0x112
#define ROW_SHR4   0x114
#define ROW_SHR8   0x118
#define WAVE_SHL1  0x130   // lane i <- lane i+1 (lane63 -> old)
#define WAVE_SHR1  0x138   // lane i <- lane i-1 (lane0  -> old)
#define ROW_BC15   0x142
#define ROW_BC31   0x143

// NOTE (R1 post-mortem): do NOT hand-write back-to-back v_*_dpp inline asm.
// gfx9 requires 2 wait states between a VALU write and a DPP read of the same
// VGPR; the builtin form lets the compiler insert the hazard nops/copies.
// The asm chain without them corrupted the scan (image absmax 0.22).
// NOTE (R3 post-mortem): NO data-dependent LDS atomics/scatter — cdf values
// cluster into few bins and the atomics serialize (bank-conflict 185k -> 14M,
// +10 us). Histogram/counting-sort inversion is a dead end on this data.
// NOTE (R5): ALL scans are now the add-form (old=0, bound_ctrl=1), the
// guaranteed-fusable v_add_f32_dpp pattern (1 instr/step). Product scans go
// through log2 domain.
__device__ __forceinline__ float scan_add_incl(float x) {
    x += DPPF(0.0f, x, ROW_SHR1, 0xf, true);
    x += DPPF(0.0f, x, ROW_SHR2, 0xf, true);
    x += DPPF(0.0f, x, ROW_SHR4, 0xf, true);
    x += DPPF(0.0f, x, ROW_SHR8, 0xf, true);
    x += DPPF(0.0f, x, ROW_BC15, 0xa, true);    // rows 1,3 only
    x += DPPF(0.0f, x, ROW_BC31, 0xc, true);    // rows 2,3 only
    return x;                      // inclusive sum; lane63 = total
}
__device__ __forceinline__ float readlanef(float x, int l) {
    return __int_as_float(__builtin_amdgcn_readlane(__float_as_int(x), l));
}

__global__ __launch_bounds__(BLOCK, 8) void nerf_render(
    const float* __restrict__ rays_o, const float* __restrict__ rays_d,
    const float* __restrict__ bgp, float* __restrict__ out, int N) {
    const int wid  = __builtin_amdgcn_readfirstlane(threadIdx.x >> 6);  // wave-uniform -> SGPR
    const int lane = threadIdx.x & 63;
    const int ray  = __builtin_amdgcn_readfirstlane(blockIdx.x * WPB + wid);
    __shared__ float cdf_s[WPB][SC];   // wave-private rows; no block barrier needed

    const float L2_10 = 3.3219280948873623f;   // log2(10)
    const float L2_E  = 1.4426950408889634f;   // log2(e)
    const float DLT   = 0.0078125f;            // 1/128
    const float C2  = -4.0f * L2_E;            // exp(-4*ssq)        = 2^(C2*ssq)
    const float C1  = -L2_E * 25.0f * DLT;     // exp(-25*e^..*DLT)  = 2^(C1*sg)
    const float C25 = -L2_E * 25.0f;           // fine: 2^(C25*sg*del)
    const float CADD = 1e-4f / 256.0f;

    float ox = rays_o[ray * 3 + 0], oy = rays_o[ray * 3 + 1], oz = rays_o[ray * 3 + 2];
    float dx = rays_d[ray * 3 + 0], dy = rays_d[ray * 3 + 1], dz = rays_d[ray * 3 + 2];
    {   // normalize direction
        float rn = frsq(dx * dx + dy * dy + dz * dz);
        dx *= rn; dy *= rn; dz *= rn;
    }
    // sigmoid direction-bias, pre-scaled for a single pk_fma per channel
    float dxn = dx * (-0.1f * L2_E), dyn = dy * (-0.1f * L2_E), dzn = dz * (-0.1f * L2_E);

    // ---------------- coarse pass: lane owns k = 4*lane .. 4*lane+3 ----------------
    // (density/alpha values BIT-FROZEN; transmittance scan is log-domain as of
    // R5 — tin moves by ~1 ulp which shifts searchsorted bins by at most 1,
    // keeping zvs/wf error at the existing 1-bin (2^-8) level)
    float zl0 = -1.0f + (float)(lane << 2) * DLT;
    float z0  = fexp2(zl0 * L2_10);
    v2f zz[2];
    zz[0].x = z0;                          zz[0].y = z0 * 1.0181517217011025f;  // 10^(1/128)
    zz[1].x = z0 * 1.0366329284377645f;    zz[1].y = z0 * 1.0554494416179205f;  // 10^(2/128),10^(3/128)

    v2f ee[2], eal[2];
#pragma unroll
    for (int p = 0; p < 2; p++) {
        v2f z  = zz[p];
        v2f px = dx * z + ox, py = dy * z + oy, pz = dz * z + oz;   // pk_fma
        v2f nsq = px * px + py * py + pz * pz;                      // pk
        v2f rn; rn.x = frsq(nsq.x); rn.y = frsq(nsq.y);
        v2f t2 = 2.0f - rn;
        v2f fs = t2 * t2;
        v2f ssq;
        ssq.x = nsq.x > 1.0f ? fs.x : nsq.x;
        ssq.y = nsq.y > 1.0f ? fs.y : nsq.y;
        v2f sr = C2 * ssq;
        v2f sg; sg.x = fexp2(sr.x); sg.y = fexp2(sr.y);             // exp(-4*ssq)
        v2f ea = C1 * sg;                                           // log2 of ee
        eal[p] = ea;
        ee[p].x = fexp2(ea.x); ee[p].y = fexp2(ea.y);               // exp(-sig*DLT)
    }
    if (lane == 63) { ee[1].y = 1.0f; eal[1].y = 0.0f; }  // last delta = 0 -> alpha 0

    // transmittance: log-domain exclusive scan (fusable add-DPP) + one exp2
    float lsum  = (eal[0].x + eal[0].y) + (eal[1].x + eal[1].y);
    float lincl = scan_add_incl(lsum);
    float lexc  = DPPF(0.0f, lincl, WAVE_SHR1, 0xf, true);   // exclusive; lane0 -> 0
    float tin   = fexp2(lexc);                               // incoming transmittance

    v2f om0 = 1.0f - ee[0], om1 = 1.0f - ee[1];
    float c1 = ee[0].x, c2 = c1 * ee[0].y, c3 = c2 * ee[1].x;
    v2f t01; t01.x = tin;      t01.y = tin * c1;
    v2f t23; t23.x = tin * c2; t23.y = tin * c3;
    v2f w01 = om0 * t01, w23 = om1 * t23;

    // reweight (scale 0.5 uniform -> cancels in normalization)
    float wprev = DPPF(0.0f, w23.y, WAVE_SHR1, 0xf, false);  // lane-1's w3; lane0 -> 0
    float wnext = DPPF(0.0f, w01.x, WAVE_SHL1, 0xf, false);  // lane+1's w0; lane63 -> 0
    float m0 = fmaxf(wprev, w01.x), m1 = fmaxf(w01.x, w01.y),
          m2 = fmaxf(w01.y, w23.x), m3 = fmaxf(w23.x, w23.y),
          m4 = fmaxf(w23.y, wnext);
    float wr0 = 0.5f * (m0 + m1) + CADD, wr1 = 0.5f * (m1 + m2) + CADD,
          wr2 = 0.5f * (m2 + m3) + CADD, wr3 = 0.5f * (m3 + m4) + CADD;

    // CDF: lane-local inclusive sums + wave add-scan
    float s0 = wr0, s1 = s0 + wr1, s2 = s1 + wr2, s3 = s2 + wr3;
    float incl = scan_add_incl(s3);
    float exb  = DPPF(0.0f, incl, WAVE_SHR1, 0xf, true);
    float invT = frcp(readlanef(incl, 63));
    v4f cdf4;
    cdf4.x = (exb + s0) * invT; cdf4.y = (exb + s1) * invT;
    cdf4.z = (exb + s2) * invT; cdf4.w = (exb + s3) * invT;
    *(v4f*)&cdf_s[wid][lane << 2] = cdf4;          // one ds_write_b128, 16B-aligned
    const float* cdf = cdf_s[wid];
    // no __syncthreads(): LDS row is wave-private; compiler orders via lgkmcnt

    // Level-1 pivots are wave-uniform register values: cdf[63]/[127]/[191]
    // live in lanes 15/31/47's cdf4.w. Bit-identical to the LDS copy.
    const float p63  = readlanef(cdf4.w, 15);
    const float p127 = readlanef(cdf4.w, 31);
    const float p191 = readlanef(cdf4.w, 47);

    // -------- inverse-CDF sampling: reg level + 2 LDS levels + final --------
    // Invariant at each level: answer inds in [base, base+S) and cdf[base+S-1] > u.
    // Bin selection bit-identical to np.searchsorted(cdf, u, 'right').
    //
    // Final level: compute cnt from cdf[base..base+2], then read BOTH
    // interpolation endpoints with one fused ds_read2_b32 at inds-1.
    // inds==0 -> c0=cdf[0], c1v=cdf[1], t<0 strictly, fmax lands f=0.
    //
    // Interpolation tail (ulp-safe, feeds only smooth outputs): no denom
    // guard — adjacent cdf gaps >= CADD*invT ~ 2e-7, Sterbenz-exact positive
    // for inds >= 1.
    float zlf[2], zvs[2];
    float ubase = (float)lane * 0.015625f;   // u = lane*2^-6 + (jj+0.5)*2^-7, exact
#pragma unroll
    for (int jj = 0; jj < 2; jj++) {
        float u = ubase + (jj ? 0.01171875f : 0.00390625f);
        int base = (((int)(p63 <= u) + (int)(p127 <= u) + (int)(p191 <= u)) << 6);
        {   // level 2: stride 16
            float qa = cdf[base + 15], qb = cdf[base + 31], qc = cdf[base + 47];
            base += (((int)(qa <= u) + (int)(qb <= u) + (int)(qc <= u)) << 4);
        }
        {   // level 3: stride 4
            float ra_ = cdf[base + 3], rb_ = cdf[base + 7], rc_ = cdf[base + 11];
            base += (((int)(ra_ <= u) + (int)(rb_ <= u) + (int)(rc_ <= u)) << 2);
        }
        // final level: stride 1 (3 adjacent reads -> b64+b32 fuse)
        float r0 = cdf[base], r1 = cdf[base + 1], r2 = cdf[base + 2];
        int cnt  = (int)(r0 <= u) + (int)(r1 <= u) + (int)(r2 <= u);
        int inds = base + cnt;
        int im1  = inds - 1;
        int ia   = im1 < 0 ? 0 : im1;               // clamp (only inds==0)
        float c0  = cdf[ia];                         // ds_read2_b32 pair
        float c1v = cdf[ia + 1];                     //   (ia+1 <= 255 always)
        float t = (u - c0) * frcp(c1v - c0);
        // inds>=1: f = (inds-1)+t; inds==0: f=0
        float f = fmaxf((float)im1 + t, 0.0f);
        zlf[jj] = fmaf(DLT, f, -1.0f);
        zvs[jj] = f * 0.00390625f;   // (zlf+1)/2 to <=1ulp: exact 2^-8 * f
    }

    // ---------------- fine render (one packed pair per lane) ----------------
    float zlf2 = DPPF(zlf[1], zlf[0], WAVE_SHL1, 0xf, false);  // zlf[2*lane+2]; lane63 -> own zlf[1] => del.y = 0
    v2f del; del.x = zlf[1] - zlf[0]; del.y = zlf2 - zlf[1];
    v2f zf;  zf.x = fexp2(zlf[0] * L2_10); zf.y = fexp2(zlf[1] * L2_10);
    // invdepth pair via one rcp: 1/zx = rzq*zy, 1/zy = rzq*zx (err ~2ulp, smooth out)
    float zq  = zf.x * zf.y;
    float rzq = frcp(zq);
    v2f invz; invz.x = rzq * zf.y; invz.y = rzq * zf.x;
    v2f px = dx * zf + ox, py = dy * zf + oy, pz = dz * zf + oz;
    v2f nsq = px * px + py * py + pz * pz;
    v2f rn; rn.x = frsq(nsq.x); rn.y = frsq(nsq.y);
    v2f t2 = 2.0f - rn;
    v2f fs = t2 * t2;
    v2f fcl = (rn * t2) * (-L2_E);     // contraction factor pre-scaled by -log2(e)
    v2f ssq, facL;
    ssq.x = nsq.x > 1.0f ? fs.x : nsq.x;  facL.x = nsq.x > 1.0f ? fcl.x : -L2_E;
    ssq.y = nsq.y > 1.0f ? fs.y : nsq.y;  facL.y = nsq.y > 1.0f ? fcl.y : -L2_E;
    v2f sr = C2 * ssq;
    v2f sg; sg.x = fexp2(sr.x); sg.y = fexp2(sr.y);        // exp(-4*ssq)
    v2f ea = (C25 * sg) * del;                             // log2(ef)  (lane63: ea.y = 0 exactly)
    v2f ef; ef.x = fexp2(ea.x); ef.y = fexp2(ea.y);        // exp(-sig*del)

    // ax = contract(p)*(-log2 e) + d-bias, with the -log2(e) folded into facL
    v2f axr = px * facL + dxn;                             // pk_fma per channel
    v2f axg = py * facL + dyn;
    v2f axb = pz * facL + dzn;
    v2f er; er.x = fexp2(axr.x); er.y = fexp2(axr.y);
    v2f eg; eg.x = fexp2(axg.x); eg.y = fexp2(axg.y);
    v2f eb; eb.x = fexp2(axb.x); eb.y = fexp2(axb.y);
    v2f dr = 1.0f + er, dg = 1.0f + eg, db = 1.0f + eb;
    // sigmoid denominators via ONE packed reciprocal of the common product:
    // 1/dr = rp*(dg*db), etc. 6 rcp -> 2 rcp + 6 pk_mul (err ~3ulp, smooth out;
    // denominators in [1.12, 9.3] so P <= ~800: no overflow/denormal risk)
    v2f m_rg = dr * dg;
    v2f m_gb = dg * db;
    v2f m_rb = dr * db;
    v2f P    = m_rg * db;
    v2f rp; rp.x = frcp(P.x); rp.y = frcp(P.y);
    v2f rv = rp * m_gb;
    v2f gv = rp * m_rb;
    v2f bv = rp * m_rg;

    // fine transmittance in LOG domain: fusable add-scan + 2 exp2
    float asum  = ea.x + ea.y;
    float tincl = scan_add_incl(asum);                       // inclusive log2-sum
    float texc  = DPPF(0.0f, tincl, WAVE_SHR1, 0xf, true);   // exclusive; lane0 -> 0
    float tinf  = fexp2(texc);                               // incoming transmittance
    float Ttot  = fexp2(readlanef(tincl, 63));               // total = 1 - sum(wf)
    float wf0 = (1.0f - ef.x) * tinf;
    float wf1 = (1.0f - ef.y) * (tinf * ef.x);
    v2f wfv; wfv.x = wf0; wfv.y = wf1;

    v2f pr = wfv * rv, pg = wfv * gv, pb = wfv * bv, pi = wfv * invz;
    float ar = scan_add_incl(pr.x + pr.y);    // lane63 = total
    float ag = scan_add_incl(pg.x + pg.y);
    float ab = scan_add_incl(pb.x + pb.y);
    float ai = scan_add_incl(pi.x + pi.y);

    // ---------------- outputs: [image N*3][wf N*128][zvs N*128][invdepth N] ----------------
    // 32-bit offsets: total elements 65536*260 < 2^25
    const unsigned NN = (unsigned)N;
    float* wf_base  = out + 3u * NN;
    float* zvs_base = wf_base + NN * (unsigned)SF;
    float* inv_base = zvs_base + NN * (unsigned)SF;
    unsigned col = (unsigned)ray * (unsigned)SF + (unsigned)(lane << 1);
    *(float2*)(wf_base + col) = make_float2(wf0, wf1);
    *(float2*)(zvs_base + col) = make_float2(zvs[0], zvs[1]);
    if (lane == 63) {
        out[(unsigned)ray * 3u + 0u] = fmaf(Ttot, bgp[0], ar);
        out[(unsigned)ray * 3u + 1u] = fmaf(Ttot, bgp[1], ag);
        out[(unsigned)ray * 3u + 2u] = fmaf(Ttot, bgp[2], ab);
        inv_base[(unsigned)ray] = ai;
    }
}

extern "C" void kernel_launch(void* const* d_in, const int* in_sizes, int n_in,
                              void* d_out, int out_size, void* d_ws, size_t ws_size,
                              hipStream_t stream) {
    const float* rays_o = (const float*)d_in[0];
    const float* rays_d = (const float*)d_in[1];
    const float* bg     = (const float*)d_in[2];
    float* out = (float*)d_out;
    int N = in_sizes[0] / 3;
    int blocks = (N + WPB - 1) / WPB;
    nerf_render<<<blocks, BLOCK, 0, stream>>>(rays_o, rays_d, bg, out, N);
}

// Round 8
// 113.687 us; speedup vs baseline: 1.0052x; 1.0052x over previous
//
#include <hip/hip_runtime.h>

#define WPB 2                // waves (rays) per block
#define BLOCK (64 * WPB)
#define SC 256               // coarse samples per ray
#define SF 128               // fine (importance) samples per ray

typedef float v2f __attribute__((ext_vector_type(2)));
typedef float v4f __attribute__((ext_vector_type(4)));

__device__ __forceinline__ float fexp2(float x) {
#if __has_builtin(__builtin_amdgcn_exp2f)
    return __builtin_amdgcn_exp2f(x);
#else
    return exp2f(x);
#endif
}
__device__ __forceinline__ float frcp(float x) {
#if __has_builtin(__builtin_amdgcn_rcpf)
    return __builtin_amdgcn_rcpf(x);
#else
    return 1.0f / x;
#endif
}
__device__ __forceinline__ float frsq(float x) {
#if __has_builtin(__builtin_amdgcn_rsqf)
    return __builtin_amdgcn_rsqf(x);
#else
    return rsqrtf(x);
#endif
}

// DPP move. bc=false: invalid/masked lanes read `oldv`.
// bc=true: invalid source lanes read 0 (masked rows still return oldv).
#define DPPF(oldv, x, ctrl, rmask, bc)                                          \
    __int_as_float(__builtin_amdgcn_update_dpp(                                 \
        __float_as_int(oldv), __float_as_int(x), (ctrl), (rmask), 0xf, (bc)))

// gfx9 DPP ctrl codes
#define ROW_SHR1   0x111
#define ROW_SHR2   0x112
#define ROW_SHR4   0x114
#define ROW_SHR8   0x118
#define WAVE_SHL1  0x130   // lane i <- lane i+1 (lane63 -> old)
#define WAVE_SHR1  0x138   // lane i <- lane i-1 (lane0  -> old)
#define ROW_BC15   0x142
#define ROW_BC31   0x143

// NOTE (R1 post-mortem): do NOT hand-write back-to-back v_*_dpp inline asm.
// gfx9 requires 2 wait states between a VALU write and a DPP read of the same
// VGPR; the builtin form lets the compiler insert the hazard nops/copies.
// NOTE (R3 post-mortem): NO data-dependent LDS atomics/scatter — cdf values
// cluster into few bins and the atomics serialize (bank-conflict 185k -> 14M,
// +10 us). Histogram/counting-sort inversion is a dead end on this data.
// NOTE (R4 calibration): exposed LDS round-trip ~0.4 us < ~12 VALU slots
// ~1.2 us — slots dominate; never spend slots to hide LDS latency here.
// NOTE (R5): ALL scans are the add-form (old=0, bound_ctrl=1), the
// guaranteed-fusable v_add_f32_dpp pattern (1 instr/step). Product scans go
// through log2 domain.
__device__ __forceinline__ float scan_add_incl(float x) {
    x += DPPF(0.0f, x, ROW_SHR1, 0xf, true);
    x += DPPF(0.0f, x, ROW_SHR2, 0xf, true);
    x += DPPF(0.0f, x, ROW_SHR4, 0xf, true);
    x += DPPF(0.0f, x, ROW_SHR8, 0xf, true);
    x += DPPF(0.0f, x, ROW_BC15, 0xa, true);    // rows 1,3 only
    x += DPPF(0.0f, x, ROW_BC31, 0xc, true);    // rows 2,3 only
    return x;                      // inclusive sum; lane63 = total
}
__device__ __forceinline__ float readlanef(float x, int l) {
    return __int_as_float(__builtin_amdgcn_readlane(__float_as_int(x), l));
}

__global__ __launch_bounds__(BLOCK, 8) void nerf_render(
    const float* __restrict__ rays_o, const float* __restrict__ rays_d,
    const float* __restrict__ bgp, float* __restrict__ out, int N) {
    const int wid  = __builtin_amdgcn_readfirstlane(threadIdx.x >> 6);  // wave-uniform -> SGPR
    const int lane = threadIdx.x & 63;
    const int ray  = __builtin_amdgcn_readfirstlane(blockIdx.x * WPB + wid);
    __shared__ float cdf_s[WPB][SC];   // wave-private rows; no block barrier needed

    const float L2_10 = 3.3219280948873623f;   // log2(10)
    const float L2_E  = 1.4426950408889634f;   // log2(e)
    const float DLT   = 0.0078125f;            // 1/128
    const float C2  = -4.0f * L2_E;            // exp(-4*ssq)        = 2^(C2*ssq)
    const float C1  = -L2_E * 25.0f * DLT;     // exp(-25*e^..*DLT)  = 2^(C1*sg)
    const float C25 = -L2_E * 25.0f;           // fine: 2^(C25*sg*del)
    const float CADD = 1e-4f / 256.0f;

    float ox = rays_o[ray * 3 + 0], oy = rays_o[ray * 3 + 1], oz = rays_o[ray * 3 + 2];
    float dx = rays_d[ray * 3 + 0], dy = rays_d[ray * 3 + 1], dz = rays_d[ray * 3 + 2];
    {   // normalize direction
        float rn = frsq(dx * dx + dy * dy + dz * dz);
        dx *= rn; dy *= rn; dz *= rn;
    }
    // sigmoid direction-bias, pre-scaled for a single pk_fma per channel
    float dxn = dx * (-0.1f * L2_E), dyn = dy * (-0.1f * L2_E), dzn = dz * (-0.1f * L2_E);

    // ---------------- coarse pass: lane owns k = 4*lane .. 4*lane+3 ----------------
    // (density/alpha values frozen; transmittance log-domain since R5 — moves
    // searchsorted bins by at most 1, keeping zvs/wf at the 1-bin 2^-8 level)
    float zl0 = -1.0f + (float)(lane << 2) * DLT;
    float z0  = fexp2(zl0 * L2_10);
    v2f zz[2];
    zz[0].x = z0;                          zz[0].y = z0 * 1.0181517217011025f;  // 10^(1/128)
    zz[1].x = z0 * 1.0366329284377645f;    zz[1].y = z0 * 1.0554494416179205f;  // 10^(2/128),10^(3/128)

    v2f ee[2], eal[2];
#pragma unroll
    for (int p = 0; p < 2; p++) {
        v2f z  = zz[p];
        v2f px = dx * z + ox, py = dy * z + oy, pz = dz * z + oz;   // pk_fma
        v2f nsq = px * px + py * py + pz * pz;                      // pk
        v2f rn; rn.x = frsq(nsq.x); rn.y = frsq(nsq.y);
        v2f t2 = 2.0f - rn;
        v2f fs = t2 * t2;
        v2f ssq;
        ssq.x = nsq.x > 1.0f ? fs.x : nsq.x;
        ssq.y = nsq.y > 1.0f ? fs.y : nsq.y;
        v2f sr = C2 * ssq;
        v2f sg; sg.x = fexp2(sr.x); sg.y = fexp2(sr.y);             // exp(-4*ssq)
        v2f ea = C1 * sg;                                           // log2 of ee
        eal[p] = ea;
        ee[p].x = fexp2(ea.x); ee[p].y = fexp2(ea.y);               // exp(-sig*DLT)
    }
    if (lane == 63) { ee[1].y = 1.0f; eal[1].y = 0.0f; }  // last delta = 0 -> alpha 0

    // transmittance: log-domain exclusive scan (fusable add-DPP) + one exp2
    float lsum  = (eal[0].x + eal[0].y) + (eal[1].x + eal[1].y);
    float lincl = scan_add_incl(lsum);
    float lexc  = DPPF(0.0f, lincl, WAVE_SHR1, 0xf, true);   // exclusive; lane0 -> 0
    float tin   = fexp2(lexc);                               // incoming transmittance

    v2f om0 = 1.0f - ee[0], om1 = 1.0f - ee[1];
    float c1 = ee[0].x, c2 = c1 * ee[0].y, c3 = c2 * ee[1].x;
    v2f t01; t01.x = tin;      t01.y = tin * c1;
    v2f t23; t23.x = tin * c2; t23.y = tin * c3;
    v2f w01 = om0 * t01, w23 = om1 * t23;

    // reweight (scale 0.5 uniform -> cancels in normalization)
    float wprev = DPPF(0.0f, w23.y, WAVE_SHR1, 0xf, false);  // lane-1's w3; lane0 -> 0
    float wnext = DPPF(0.0f, w01.x, WAVE_SHL1, 0xf, false);  // lane+1's w0; lane63 -> 0
    float m0 = fmaxf(wprev, w01.x), m1 = fmaxf(w01.x, w01.y),
          m2 = fmaxf(w01.y, w23.x), m3 = fmaxf(w23.x, w23.y),
          m4 = fmaxf(w23.y, wnext);
    float wr0 = 0.5f * (m0 + m1) + CADD, wr1 = 0.5f * (m1 + m2) + CADD,
          wr2 = 0.5f * (m2 + m3) + CADD, wr3 = 0.5f * (m3 + m4) + CADD;

    // CDF (R6: UNNORMALIZED — searchsorted compares against u' = u*T instead
    // of dividing the cdf by T; saves 4 muls + 1 rcp/wave. The interp ratio
    // t = (u'-c0)/(c1v-c0) is scale-invariant up to ulps; boundary flips move
    // bins by <=1, same accepted class as R5's log-domain tin.)
    float s0 = wr0, s1 = s0 + wr1, s2 = s1 + wr2, s3 = s2 + wr3;
    float incl = scan_add_incl(s3);
    float exb  = DPPF(0.0f, incl, WAVE_SHR1, 0xf, true);
    float T    = readlanef(incl, 63);                // total (unnormalized)
    v4f cdf4;
    cdf4.x = exb + s0; cdf4.y = exb + s1;
    cdf4.z = exb + s2; cdf4.w = exb + s3;
    *(v4f*)&cdf_s[wid][lane << 2] = cdf4;          // one ds_write_b128, 16B-aligned
    const float* cdf = cdf_s[wid];
    // no __syncthreads(): LDS row is wave-private; compiler orders via lgkmcnt

    // Level-1 pivots are wave-uniform register values: cdf[63]/[127]/[191]
    // live in lanes 15/31/47's cdf4.w. Bit-identical to the LDS copy.
    const float p63  = readlanef(cdf4.w, 15);
    const float p127 = readlanef(cdf4.w, 31);
    const float p191 = readlanef(cdf4.w, 47);

    // -------- inverse-CDF sampling: reg level + 2 LDS levels + final --------
    // Invariant at each level: answer inds in [base, base+S) and cdf[base+S-1] > u'.
    // R6: levels use nested SELECTS instead of sum-of-compares — for strictly
    // increasing pivots (wr >= CADD > 0) the select tree is identical to the
    // compare-sum, in exactly 3 v_cmp + 3 v_cndmask with pre-shifted constants.
    //
    // Final level: cnt from cdf[base..base+2], endpoints via fused ds_read2.
    // inds==0 -> t < 0 strictly, fmax lands f=0 (reference: b0=b1=bins[0]).
    // No denom guard: unnormalized gaps = wr >= CADD exactly.
    float zlf[2], zvs[2];
    float laneT = ((float)lane * 0.015625f) * T;     // ubase*T
#pragma unroll
    for (int jj = 0; jj < 2; jj++) {
        float u = fmaf(jj ? 0.01171875f : 0.00390625f, T, laneT);   // u' = u*T (ulp-class)
        int bhi = (p191 <= u) ? 192 : 128;
        int blo = (p63  <= u) ? 64  : 0;
        int base = (p127 <= u) ? bhi : blo;
        {   // level 2: stride 16
            float qa = cdf[base + 15], qb = cdf[base + 31], qc = cdf[base + 47];
            int chi = (qc <= u) ? 48 : 32;
            int clo = (qa <= u) ? 16 : 0;
            base += (qb <= u) ? chi : clo;
        }
        {   // level 3: stride 4
            float ra_ = cdf[base + 3], rb_ = cdf[base + 7], rc_ = cdf[base + 11];
            int dhi = (rc_ <= u) ? 12 : 8;
            int dlo = (ra_ <= u) ? 4 : 0;
            base += (rb_ <= u) ? dhi : dlo;
        }
        // final level: stride 1 (3 adjacent reads -> b64+b32 fuse)
        float r0 = cdf[base], r1 = cdf[base + 1], r2 = cdf[base + 2];
        int cnt  = (int)(r0 <= u) + (int)(r1 <= u) + (int)(r2 <= u);
        int inds = base + cnt;
        int im1  = inds - 1;
        int ia   = im1 < 0 ? 0 : im1;               // clamp (only inds==0)
        float c0  = cdf[ia];                         // ds_read2_b32 pair
        float c1v = cdf[ia + 1];                     //   (ia+1 <= 255 always)
        float t = (u - c0) * frcp(c1v - c0);
        // inds>=1: f = (inds-1)+t; inds==0: t<0 -> f=0
        float f = fmaxf((float)im1 + t, 0.0f);
        zlf[jj] = fmaf(DLT, f, -1.0f);
        zvs[jj] = f * 0.00390625f;   // (zlf+1)/2 to <=1ulp: exact 2^-8 * f
    }

    // ---------------- fine render (one packed pair per lane) ----------------
    float zlf2 = DPPF(zlf[1], zlf[0], WAVE_SHL1, 0xf, false);  // zlf[2*lane+2]; lane63 -> own zlf[1] => del.y = 0
    v2f del; del.x = zlf[1] - zlf[0]; del.y = zlf2 - zlf[1];
    v2f zf;  zf.x = fexp2(zlf[0] * L2_10); zf.y = fexp2(zlf[1] * L2_10);
    // invdepth pair via one rcp: 1/zx = rzq*zy, 1/zy = rzq*zx (err ~2ulp, smooth out)
    float zq  = zf.x * zf.y;
    float rzq = frcp(zq);
    v2f invz; invz.x = rzq * zf.y; invz.y = rzq * zf.x;
    v2f px = dx * zf + ox, py = dy * zf + oy, pz = dz * zf + oz;
    v2f nsq = px * px + py * py + pz * pz;
    v2f rn; rn.x = frsq(nsq.x); rn.y = frsq(nsq.y);
    v2f t2 = 2.0f - rn;
    v2f fs = t2 * t2;
    v2f fcl = (rn * t2) * (-L2_E);     // contraction factor pre-scaled by -log2(e)
    v2f ssq, facL;
    ssq.x = nsq.x > 1.0f ? fs.x : nsq.x;  facL.x = nsq.x > 1.0f ? fcl.x : -L2_E;
    ssq.y = nsq.y > 1.0f ? fs.y : nsq.y;  facL.y = nsq.y > 1.0f ? fcl.y : -L2_E;
    v2f sr = C2 * ssq;
    v2f sg; sg.x = fexp2(sr.x); sg.y = fexp2(sr.y);        // exp(-4*ssq)
    v2f ea = (C25 * sg) * del;                             // log2(ef)  (lane63: ea.y = 0 exactly)
    v2f ef; ef.x = fexp2(ea.x); ef.y = fexp2(ea.y);        // exp(-sig*del)

    // ax = contract(p)*(-log2 e) + d-bias, with the -log2(e) folded into facL
    v2f axr = px * facL + dxn;                             // pk_fma per channel
    v2f axg = py * facL + dyn;
    v2f axb = pz * facL + dzn;
    v2f er; er.x = fexp2(axr.x); er.y = fexp2(axr.y);
    v2f eg; eg.x = fexp2(axg.x); eg.y = fexp2(axg.y);
    v2f eb; eb.x = fexp2(axb.x); eb.y = fexp2(axb.y);
    v2f dr = 1.0f + er, dg = 1.0f + eg, db = 1.0f + eb;
    // sigmoid denominators via ONE packed reciprocal of the common product:
    // 1/dr = rp*(dg*db), etc. 6 rcp -> 2 rcp + 6 pk_mul (err ~3ulp, smooth out;
    // denominators in [1.12, 9.3] so P <= ~800: no overflow/denormal risk)
    v2f m_rg = dr * dg;
    v2f m_gb = dg * db;
    v2f m_rb = dr * db;
    v2f P    = m_rg * db;
    v2f rp; rp.x = frcp(P.x); rp.y = frcp(P.y);
    v2f rv = rp * m_gb;
    v2f gv = rp * m_rb;
    v2f bv = rp * m_rg;

    // fine transmittance in LOG domain: fusable add-scan + 2 exp2
    float asum  = ea.x + ea.y;
    float tincl = scan_add_incl(asum);                       // inclusive log2-sum
    float texc  = DPPF(0.0f, tincl, WAVE_SHR1, 0xf, true);   // exclusive; lane0 -> 0
    float tinf  = fexp2(texc);                               // incoming transmittance
    float Ttot  = fexp2(readlanef(tincl, 63));               // total = 1 - sum(wf)
    float wf0 = (1.0f - ef.x) * tinf;
    float wf1 = (1.0f - ef.y) * (tinf * ef.x);
    v2f wfv; wfv.x = wf0; wfv.y = wf1;

    v2f pr = wfv * rv, pg = wfv * gv, pb = wfv * bv, pi = wfv * invz;
    float ar = scan_add_incl(pr.x + pr.y);    // lane63 = total
    float ag = scan_add_incl(pg.x + pg.y);
    float ab = scan_add_incl(pb.x + pb.y);
    float ai = scan_add_incl(pi.x + pi.y);

    // ---------------- outputs: [image N*3][wf N*128][zvs N*128][invdepth N] ----------------
    // 32-bit offsets: total elements 65536*260 < 2^25
    const unsigned NN = (unsigned)N;
    float* wf_base  = out + 3u * NN;
    float* zvs_base = wf_base + NN * (unsigned)SF;
    float* inv_base = zvs_base + NN * (unsigned)SF;
    unsigned col = (unsigned)ray * (unsigned)SF + (unsigned)(lane << 1);
    *(float2*)(wf_base + col) = make_float2(wf0, wf1);
    *(float2*)(zvs_base + col) = make_float2(zvs[0], zvs[1]);
    if (lane == 63) {
        out[(unsigned)ray * 3u + 0u] = fmaf(Ttot, bgp[0], ar);
        out[(unsigned)ray * 3u + 1u] = fmaf(Ttot, bgp[1], ag);
        out[(unsigned)ray * 3u + 2u] = fmaf(Ttot, bgp[2], ab);
        inv_base[(unsigned)ray] = ai;
    }
}

extern "C" void kernel_launch(void* const* d_in, const int* in_sizes, int n_in,
                              void* d_out, int out_size, void* d_ws, size_t ws_size,
                              hipStream_t stream) {
    const float* rays_o = (const float*)d_in[0];
    const float* rays_d = (const float*)d_in[1];
    const float* bg     = (const float*)d_in[2];
    float* out = (float*)d_out;
    int N = in_sizes[0] / 3;
    int blocks = (N + WPB - 1) / WPB;
    nerf_render<<<blocks, BLOCK, 0, stream>>>(rays_o, rays_d, bg, out, N);
}

// Round 9
// 111.376 us; speedup vs baseline: 1.0261x; 1.0207x over previous
//
#include <hip/hip_runtime.h>

#define WPB 2                // waves (rays) per block
#define BLOCK (64 * WPB)
#define SC 256               // coarse samples per ray
#define SF 128               // fine (importance) samples per ray

typedef float v2f __attribute__((ext_vector_type(2)));
typedef float v4f __attribute__((ext_vector_type(4)));

__device__ __forceinline__ float fexp2(float x) {
#if __has_builtin(__builtin_amdgcn_exp2f)
    return __builtin_amdgcn_exp2f(x);
#else
    return exp2f(x);
#endif
}
__device__ __forceinline__ float frcp(float x) {
#if __has_builtin(__builtin_amdgcn_rcpf)
    return __builtin_amdgcn_rcpf(x);
#else
    return 1.0f / x;
#endif
}
__device__ __forceinline__ float frsq(float x) {
#if __has_builtin(__builtin_amdgcn_rsqf)
    return __builtin_amdgcn_rsqf(x);
#else
    return rsqrtf(x);
#endif
}

// DPP move. bc=false: invalid/masked lanes read `oldv`.
// bc=true: invalid source lanes read 0 (masked rows still return oldv).
#define DPPF(oldv, x, ctrl, rmask, bc)                                          \
    __int_as_float(__builtin_amdgcn_update_dpp(                                 \
        __float_as_int(oldv), __float_as_int(x), (ctrl), (rmask), 0xf, (bc)))

// gfx9 DPP ctrl codes
#define ROW_SHR1   0x111
#define ROW_SHR2   0x112
#define ROW_SHR4   0x114
#define ROW_SHR8   0x118
#define WAVE_SHL1  0x130   // lane i <- lane i+1 (lane63 -> old)
#define WAVE_SHR1  0x138   // lane i <- lane i-1 (lane0  -> old)
#define ROW_BC15   0x142
#define ROW_BC31   0x143

// NOTE (R1 post-mortem): do NOT hand-write back-to-back v_*_dpp inline asm.
// gfx9 requires 2 wait states between a VALU write and a DPP read of the same
// VGPR; the builtin form lets the compiler insert the hazard nops/copies.
// NOTE (R3 post-mortem): NO data-dependent LDS atomics/scatter — cdf values
// cluster into few bins and the atomics serialize (bank-conflict 185k -> 14M,
// +10 us). Histogram/counting-sort inversion is a dead end on this data.
// NOTE (R4 calibration): exposed LDS round-trip ~0.4 us < ~12 VALU slots
// ~1.2 us — slots dominate; never spend slots to hide LDS latency here.
// NOTE (R6 post-mortem): re-expressing selection logic (select-tree vs
// compare-sum) is NEUTRAL — compiler already emits the compact form. Only
// mechanically-guaranteed instruction removals (builtin DPP count, trans
// count, LDS op count) move the needle.
__device__ __forceinline__ float scan_add_incl(float x) {
    x += DPPF(0.0f, x, ROW_SHR1, 0xf, true);
    x += DPPF(0.0f, x, ROW_SHR2, 0xf, true);
    x += DPPF(0.0f, x, ROW_SHR4, 0xf, true);
    x += DPPF(0.0f, x, ROW_SHR8, 0xf, true);
    x += DPPF(0.0f, x, ROW_BC15, 0xa, true);    // rows 1,3 only
    x += DPPF(0.0f, x, ROW_BC31, 0xc, true);    // rows 2,3 only
    return x;                      // inclusive sum; lane63 = total
}
__device__ __forceinline__ float readlanef(float x, int l) {
    return __int_as_float(__builtin_amdgcn_readlane(__float_as_int(x), l));
}

__global__ __launch_bounds__(BLOCK, 8) void nerf_render(
    const float* __restrict__ rays_o, const float* __restrict__ rays_d,
    const float* __restrict__ bgp, float* __restrict__ out, int N) {
    const int wid  = __builtin_amdgcn_readfirstlane(threadIdx.x >> 6);  // wave-uniform -> SGPR
    const int lane = threadIdx.x & 63;
    const int ray  = __builtin_amdgcn_readfirstlane(blockIdx.x * WPB + wid);
    __shared__ float cdf_s[WPB][SC];   // wave-private rows; no block barrier needed

    const float L2_10 = 3.3219280948873623f;   // log2(10)
    const float L2_E  = 1.4426950408889634f;   // log2(e)
    const float DLT   = 0.0078125f;            // 1/128
    const float C2  = -4.0f * L2_E;            // exp(-4*ssq)        = 2^(C2*ssq)
    const float C1  = -L2_E * 25.0f * DLT;     // exp(-25*e^..*DLT)  = 2^(C1*sg)
    const float C25 = -L2_E * 25.0f;           // fine: 2^(C25*sg*del)
    const float CADD = 1e-4f / 256.0f;

    float ox = rays_o[ray * 3 + 0], oy = rays_o[ray * 3 + 1], oz = rays_o[ray * 3 + 2];
    float dx = rays_d[ray * 3 + 0], dy = rays_d[ray * 3 + 1], dz = rays_d[ray * 3 + 2];
    {   // normalize direction
        float rn = frsq(dx * dx + dy * dy + dz * dz);
        dx *= rn; dy *= rn; dz *= rn;
    }
    // sigmoid direction-bias, pre-scaled for a single pk_fma per channel
    float dxn = dx * (-0.1f * L2_E), dyn = dy * (-0.1f * L2_E), dzn = dz * (-0.1f * L2_E);

    // ---------------- coarse pass: lane owns k = 4*lane .. 4*lane+3 ----------------
    // (density/alpha values frozen; transmittance log-domain since R5 — moves
    // searchsorted bins by at most 1, keeping zvs/wf at the 1-bin 2^-8 level)
    float zl0 = -1.0f + (float)(lane << 2) * DLT;
    float z0  = fexp2(zl0 * L2_10);
    v2f zz[2];
    zz[0].x = z0;                          zz[0].y = z0 * 1.0181517217011025f;  // 10^(1/128)
    zz[1].x = z0 * 1.0366329284377645f;    zz[1].y = z0 * 1.0554494416179205f;  // 10^(2/128),10^(3/128)

    v2f ee[2], eal[2];
#pragma unroll
    for (int p = 0; p < 2; p++) {
        v2f z  = zz[p];
        v2f px = dx * z + ox, py = dy * z + oy, pz = dz * z + oz;   // pk_fma
        v2f nsq = px * px + py * py + pz * pz;                      // pk
        v2f rn; rn.x = frsq(nsq.x); rn.y = frsq(nsq.y);
        v2f t2 = 2.0f - rn;
        v2f fs = t2 * t2;
        v2f ssq;
        ssq.x = nsq.x > 1.0f ? fs.x : nsq.x;
        ssq.y = nsq.y > 1.0f ? fs.y : nsq.y;
        v2f sr = C2 * ssq;
        v2f sg; sg.x = fexp2(sr.x); sg.y = fexp2(sr.y);             // exp(-4*ssq)
        v2f ea = C1 * sg;                                           // log2 of ee
        eal[p] = ea;
        ee[p].x = fexp2(ea.x); ee[p].y = fexp2(ea.y);               // exp(-sig*DLT)
    }
    if (lane == 63) { ee[1].y = 1.0f; eal[1].y = 0.0f; }  // last delta = 0 -> alpha 0

    // transmittance: log-domain exclusive scan (fusable add-DPP) + one exp2
    float lsum  = (eal[0].x + eal[0].y) + (eal[1].x + eal[1].y);
    float lincl = scan_add_incl(lsum);
    float lexc  = DPPF(0.0f, lincl, WAVE_SHR1, 0xf, true);   // exclusive; lane0 -> 0
    float tin   = fexp2(lexc);                               // incoming transmittance

    v2f om0 = 1.0f - ee[0], om1 = 1.0f - ee[1];
    float c1 = ee[0].x, c2 = c1 * ee[0].y, c3 = c2 * ee[1].x;
    v2f t01; t01.x = tin;      t01.y = tin * c1;
    v2f t23; t23.x = tin * c2; t23.y = tin * c3;
    v2f w01 = om0 * t01, w23 = om1 * t23;

    // reweight (scale 0.5 uniform -> cancels in normalization)
    float wprev = DPPF(0.0f, w23.y, WAVE_SHR1, 0xf, false);  // lane-1's w3; lane0 -> 0
    float wnext = DPPF(0.0f, w01.x, WAVE_SHL1, 0xf, false);  // lane+1's w0; lane63 -> 0
    float m0 = fmaxf(wprev, w01.x), m1 = fmaxf(w01.x, w01.y),
          m2 = fmaxf(w01.y, w23.x), m3 = fmaxf(w23.x, w23.y),
          m4 = fmaxf(w23.y, wnext);
    float wr0 = 0.5f * (m0 + m1) + CADD, wr1 = 0.5f * (m1 + m2) + CADD,
          wr2 = 0.5f * (m2 + m3) + CADD, wr3 = 0.5f * (m3 + m4) + CADD;

    // CDF (unnormalized since R6: searchsorted compares against u' = u*T;
    // interp ratio is scale-invariant; boundary flips move bins <=1)
    float s0 = wr0, s1 = s0 + wr1, s2 = s1 + wr2, s3 = s2 + wr3;
    float incl = scan_add_incl(s3);
    float exb  = DPPF(0.0f, incl, WAVE_SHR1, 0xf, true);
    float T    = readlanef(incl, 63);                // total (unnormalized)
    v4f cdf4;
    cdf4.x = exb + s0; cdf4.y = exb + s1;
    cdf4.z = exb + s2; cdf4.w = exb + s3;
    *(v4f*)&cdf_s[wid][lane << 2] = cdf4;          // one ds_write_b128, 16B-aligned
    const float* cdf = cdf_s[wid];
    // no __syncthreads(): LDS row is wave-private; compiler orders via lgkmcnt

    // Level-1 pivots are wave-uniform register values: cdf[63]/[127]/[191]
    // live in lanes 15/31/47's cdf4.w. Bit-identical to the LDS copy.
    const float p63  = readlanef(cdf4.w, 15);
    const float p127 = readlanef(cdf4.w, 31);
    const float p191 = readlanef(cdf4.w, 47);

    // -------- inverse-CDF sampling: reg level + 2 LDS levels + final --------
    // Invariant at each level: answer inds in [base, base+S) and cdf[base+S-1] > u'.
    // Bin selection bit-identical to np.searchsorted(cdf, u, 'right').
    // Final level: cnt from cdf[base..base+2], endpoints via fused ds_read2.
    // inds==0 -> t < 0 strictly, fmax lands f=0 (reference: b0=b1=bins[0]).
    // No denom guard: unnormalized gaps = wr >= CADD exactly.
    float zlf[2], zvs[2];
    float laneT = ((float)lane * 0.015625f) * T;     // ubase*T
#pragma unroll
    for (int jj = 0; jj < 2; jj++) {
        float u = fmaf(jj ? 0.01171875f : 0.00390625f, T, laneT);   // u' = u*T (ulp-class)
        int bhi = (p191 <= u) ? 192 : 128;
        int blo = (p63  <= u) ? 64  : 0;
        int base = (p127 <= u) ? bhi : blo;
        {   // level 2: stride 16
            float qa = cdf[base + 15], qb = cdf[base + 31], qc = cdf[base + 47];
            int chi = (qc <= u) ? 48 : 32;
            int clo = (qa <= u) ? 16 : 0;
            base += (qb <= u) ? chi : clo;
        }
        {   // level 3: stride 4
            float ra_ = cdf[base + 3], rb_ = cdf[base + 7], rc_ = cdf[base + 11];
            int dhi = (rc_ <= u) ? 12 : 8;
            int dlo = (ra_ <= u) ? 4 : 0;
            base += (rb_ <= u) ? dhi : dlo;
        }
        // final level: stride 1 (3 adjacent reads -> b64+b32 fuse)
        float r0 = cdf[base], r1 = cdf[base + 1], r2 = cdf[base + 2];
        int cnt  = (int)(r0 <= u) + (int)(r1 <= u) + (int)(r2 <= u);
        int inds = base + cnt;
        int im1  = inds - 1;
        int ia   = im1 < 0 ? 0 : im1;               // clamp (only inds==0)
        float c0  = cdf[ia];                         // ds_read2_b32 pair
        float c1v = cdf[ia + 1];                     //   (ia+1 <= 255 always)
        float t = (u - c0) * frcp(c1v - c0);
        // inds>=1: f = (inds-1)+t; inds==0: t<0 -> f=0
        float f = fmaxf((float)im1 + t, 0.0f);
        zlf[jj] = fmaf(DLT, f, -1.0f);
        zvs[jj] = f * 0.00390625f;   // (zlf+1)/2 to <=1ulp: exact 2^-8 * f
    }

    // ---------------- fine render (one packed pair per lane) ----------------
    float zlf2 = DPPF(zlf[1], zlf[0], WAVE_SHL1, 0xf, false);  // zlf[2*lane+2]; lane63 -> own zlf[1] => del.y = 0
    v2f del; del.x = zlf[1] - zlf[0]; del.y = zlf2 - zlf[1];
    v2f zf;  zf.x = fexp2(zlf[0] * L2_10); zf.y = fexp2(zlf[1] * L2_10);
    // invdepth pair via one rcp: 1/zx = rzq*zy, 1/zy = rzq*zx (err ~2ulp, smooth out)
    float zq  = zf.x * zf.y;
    float rzq = frcp(zq);
    v2f invz; invz.x = rzq * zf.y; invz.y = rzq * zf.x;
    v2f px = dx * zf + ox, py = dy * zf + oy, pz = dz * zf + oz;
    v2f nsq = px * px + py * py + pz * pz;
    v2f rn; rn.x = frsq(nsq.x); rn.y = frsq(nsq.y);
    v2f t2 = 2.0f - rn;
    v2f fs = t2 * t2;
    v2f fcl = (rn * t2) * (-L2_E);     // contraction factor pre-scaled by -log2(e)
    v2f ssq, facL;
    ssq.x = nsq.x > 1.0f ? fs.x : nsq.x;  facL.x = nsq.x > 1.0f ? fcl.x : -L2_E;
    ssq.y = nsq.y > 1.0f ? fs.y : nsq.y;  facL.y = nsq.y > 1.0f ? fcl.y : -L2_E;
    v2f sr = C2 * ssq;
    v2f sg; sg.x = fexp2(sr.x); sg.y = fexp2(sr.y);        // exp(-4*ssq)
    v2f ea = (C25 * sg) * del;                             // log2(ef)  (lane63: ea.y = 0 exactly)
    v2f ef; ef.x = fexp2(ea.x); ef.y = fexp2(ea.y);        // exp(-sig*del)

    // ax = contract(p)*(-log2 e) + d-bias, with the -log2(e) folded into facL
    v2f axr = px * facL + dxn;                             // pk_fma per channel
    v2f axg = py * facL + dyn;
    v2f axb = pz * facL + dzn;
    v2f er; er.x = fexp2(axr.x); er.y = fexp2(axr.y);
    v2f eg; eg.x = fexp2(axg.x); eg.y = fexp2(axg.y);
    v2f eb; eb.x = fexp2(axb.x); eb.y = fexp2(axb.y);
    v2f dr = 1.0f + er, dg = 1.0f + eg, db = 1.0f + eb;
    // sigmoid denominators via ONE packed reciprocal of the common product:
    // 1/dr = rp*(dg*db), etc. 6 rcp -> 2 rcp + 6 pk_mul (err ~3ulp, smooth out;
    // denominators in [1.12, 9.3] so P <= ~800: no overflow/denormal risk)
    v2f m_rg = dr * dg;
    v2f m_gb = dg * db;
    v2f m_rb = dr * db;
    v2f P    = m_rg * db;
    v2f rp; rp.x = frcp(P.x); rp.y = frcp(P.y);
    v2f rv = rp * m_gb;
    v2f gv = rp * m_rb;
    v2f bv = rp * m_rg;

    // fine transmittance in LOG domain: fusable add-scan + 2 exp2
    float asum  = ea.x + ea.y;
    float tincl = scan_add_incl(asum);                       // inclusive log2-sum
    float texc  = DPPF(0.0f, tincl, WAVE_SHR1, 0xf, true);   // exclusive; lane0 -> 0
    float tinf  = fexp2(texc);                               // incoming transmittance
    float Ttot  = fexp2(readlanef(tincl, 63));               // total = 1 - sum(wf)
    float wf0 = (1.0f - ef.x) * tinf;
    float wf1 = (1.0f - ef.y) * (tinf * ef.x);
    v2f wfv; wfv.x = wf0; wfv.y = wf1;

    v2f pr = wfv * rv, pg = wfv * gv, pb = wfv * bv, pi = wfv * invz;

    // ---------------- outputs: [image N*3][wf N*128][zvs N*128][invdepth N] ----------------
    // 32-bit offsets: total elements 65536*260 < 2^25
    const unsigned NN = (unsigned)N;
    float* wf_base  = out + 3u * NN;
    float* zvs_base = wf_base + NN * (unsigned)SF;
    float* inv_base = zvs_base + NN * (unsigned)SF;
    unsigned col = (unsigned)ray * (unsigned)SF + (unsigned)(lane << 1);
    *(float2*)(wf_base + col) = make_float2(wf0, wf1);
    *(float2*)(zvs_base + col) = make_float2(zvs[0], zvs[1]);

    // R7: transpose-reduce the 4 per-lane partial sums via LDS (cdf_s row is
    // dead after sampling). Replaces 4 independent 6-step DPP butterflies
    // (24 v_add_f32_dpp) with 1 ds_write_b128 + 2 ds_read2_b32 + 3 adds +
    // ONE 4-step row-local scan: quantity q = lane>>4 reduced by row q,
    // totals land in lanes 15/31/47/63. Sum reassociation only perturbs
    // image/invdepth (~1e-6 on ~0.18 thresholds); wf/zvs untouched.
    {
        v4f part;
        part.x = pr.x + pr.y; part.y = pg.x + pg.y;
        part.z = pb.x + pb.y; part.w = pi.x + pi.y;
        *(v4f*)&cdf_s[wid][lane << 2] = part;        // overwrite cdf row
    }
    const int q = lane >> 4, i16 = lane & 15;
    const float* pbase = cdf_s[wid];
    int e0 = (i16 << 2) + q;
    float a0 = pbase[e0],       a1 = pbase[e0 + 64];    // ds_read2_b32 (2-way bank, free)
    float a2 = pbase[e0 + 128], a3 = pbase[e0 + 192];   // ds_read2_b32
    float rsum = (a0 + a1) + (a2 + a3);
    rsum += DPPF(0.0f, rsum, ROW_SHR1, 0xf, true);   // 16-lane row scan;
    rsum += DPPF(0.0f, rsum, ROW_SHR2, 0xf, true);   // last lane of each row
    rsum += DPPF(0.0f, rsum, ROW_SHR4, 0xf, true);   // holds the row total
    rsum += DPPF(0.0f, rsum, ROW_SHR8, 0xf, true);
    float ar = readlanef(rsum, 15);
    float ag = readlanef(rsum, 31);
    float ab = readlanef(rsum, 47);
    if (lane == 63) {
        out[(unsigned)ray * 3u + 0u] = fmaf(Ttot, bgp[0], ar);
        out[(unsigned)ray * 3u + 1u] = fmaf(Ttot, bgp[1], ag);
        out[(unsigned)ray * 3u + 2u] = fmaf(Ttot, bgp[2], ab);
        inv_base[(unsigned)ray] = rsum;              // lane63 = ai total
    }
}

extern "C" void kernel_launch(void* const* d_in, const int* in_sizes, int n_in,
                              void* d_out, int out_size, void* d_ws, size_t ws_size,
                              hipStream_t stream) {
    const float* rays_o = (const float*)d_in[0];
    const float* rays_d = (const float*)d_in[1];
    const float* bg     = (const float*)d_in[2];
    float* out = (float*)d_out;
    int N = in_sizes[0] / 3;
    int blocks = (N + WPB - 1) / WPB;
    nerf_render<<<blocks, BLOCK, 0, stream>>>(rays_o, rays_d, bg, out, N);
}